// Round 1
// baseline (311.058 us; speedup 1.0000x reference)
//
#include <hip/hip_runtime.h>
#include <hip/hip_bf16.h>
#include <math.h>

// CausalFullAttention: out[b,l,h,d] = softmax_s( 0.125*(q.k + bias[l,s]), s<=l ) @ V
// B=4 L=S=2048 H=8 E=D=64, fp32 in/out, bf16 MFMA compute.

typedef __bf16 bf16x8 __attribute__((ext_vector_type(8)));
typedef __bf16 bf16x4 __attribute__((ext_vector_type(4)));
typedef float  f32x4  __attribute__((ext_vector_type(4)));

#define NB 4
#define NL 2048
#define NS 2048
#define NH 8
#define NE 64
#define ND 64

__device__ __forceinline__ int swz(int d) { return ((d ^ (d >> 3)) & 7) << 3; }

__device__ __forceinline__ bf16x8 cvt8s(float4 a, float4 b, float sc) {
    bf16x8 r;
    r[0] = (__bf16)(a.x * sc); r[1] = (__bf16)(a.y * sc);
    r[2] = (__bf16)(a.z * sc); r[3] = (__bf16)(a.w * sc);
    r[4] = (__bf16)(b.x * sc); r[5] = (__bf16)(b.y * sc);
    r[6] = (__bf16)(b.z * sc); r[7] = (__bf16)(b.w * sc);
    return r;
}
__device__ __forceinline__ bf16x8 cvt8(float4 a, float4 b) {
    bf16x8 r;
    r[0] = (__bf16)a.x; r[1] = (__bf16)a.y; r[2] = (__bf16)a.z; r[3] = (__bf16)a.w;
    r[4] = (__bf16)b.x; r[5] = (__bf16)b.y; r[6] = (__bf16)b.z; r[7] = (__bf16)b.w;
    return r;
}

__global__ __launch_bounds__(256)
void fa_fwd(const float* __restrict__ Q, const float* __restrict__ K,
            const float* __restrict__ V, const float* __restrict__ Bias,
            float* __restrict__ Out)
{
    // K tile row-major [kv][e], +8 pad breaks the 128B-row 16-way bank conflict.
    __shared__ __bf16 Klds[64][72];
    // V tile transposed [d][kv], XOR-swizzled within rows (read side must be 2-way max).
    __shared__ __bf16 Vlds[64][64];
    // per-wave P bounce buffer for the softmax->PV re-fragmentation
    __shared__ __bf16 Plds[4][16][72];

    const int tid  = threadIdx.x;
    const int w    = tid >> 6, lane = tid & 63;
    const int g    = lane >> 4, li = lane & 15;
    const int qt   = blockIdx.x, bh = blockIdx.y;
    const int b    = bh >> 3, h = bh & 7;
    const int qb   = qt << 6;
    const int qw   = qb + (w << 4);   // this wave's first q row

    // softmax( scale*(qk + bias) ) -> base-2 domain, fold scale*log2(e) into q and bias
    const float SC = 0.125f * 1.44269504088896340736f;

    // Q fragments: A[m=li][k = eh*32 + g*8 + j], loaded once, pre-scaled
    bf16x8 qa[2];
    {
        const float* qp = Q + (((size_t)(b * NL + qw + li)) * NH + h) * NE;
        #pragma unroll
        for (int eh = 0; eh < 2; ++eh) {
            const int e0 = eh * 32 + g * 8;
            float4 f0 = *(const float4*)(qp + e0);
            float4 f1 = *(const float4*)(qp + e0 + 4);
            qa[eh] = cvt8s(f0, f1, SC);
        }
    }

    f32x4 o[4] = {};                      // O accum: row = g*4+j, col = dt*16+li
    float m_run[4] = {-INFINITY, -INFINITY, -INFINITY, -INFINITY};
    float l_run[4] = {};

    const int ntiles = qt + 1;            // causal: kv tiles 0 .. qb/64

    // cooperative staging indices
    const int skv = tid >> 2,        se0 = (tid & 3) << 4;   // K: row, e-quarter
    const int vkv = (tid >> 4) << 2, vd0 = (tid & 15) << 2;  // V: 4kv x 4d sub-block

    for (int t = 0; t < ntiles; ++t) {
        const int kv0 = t << 6;
        __syncthreads();   // previous tile's LDS reads complete before overwrite
        // --- stage K tile: global fp32 -> LDS bf16, coalesced rows ---
        {
            const float* kp = K + (((size_t)(b * NS + kv0 + skv)) * NH + h) * NE + se0;
            float4 a0 = ((const float4*)kp)[0];
            float4 a1 = ((const float4*)kp)[1];
            float4 a2 = ((const float4*)kp)[2];
            float4 a3 = ((const float4*)kp)[3];
            *(bf16x8*)&Klds[skv][se0]     = cvt8(a0, a1);
            *(bf16x8*)&Klds[skv][se0 + 8] = cvt8(a2, a3);
        }
        // --- stage V tile transposed: Vlds[d][kv^swz(d)] ---
        {
            const float* vp = V + (((size_t)(b * NS + kv0 + vkv)) * NH + h) * ND + vd0;
            float4 r0 = *(const float4*)(vp);
            float4 r1 = *(const float4*)(vp + NH * ND);
            float4 r2 = *(const float4*)(vp + 2 * NH * ND);
            float4 r3 = *(const float4*)(vp + 3 * NH * ND);
            bf16x4 c;
            c[0]=(__bf16)r0.x; c[1]=(__bf16)r1.x; c[2]=(__bf16)r2.x; c[3]=(__bf16)r3.x;
            *(bf16x4*)&Vlds[vd0 + 0][vkv ^ swz(vd0 + 0)] = c;
            c[0]=(__bf16)r0.y; c[1]=(__bf16)r1.y; c[2]=(__bf16)r2.y; c[3]=(__bf16)r3.y;
            *(bf16x4*)&Vlds[vd0 + 1][vkv ^ swz(vd0 + 1)] = c;
            c[0]=(__bf16)r0.z; c[1]=(__bf16)r1.z; c[2]=(__bf16)r2.z; c[3]=(__bf16)r3.z;
            *(bf16x4*)&Vlds[vd0 + 2][vkv ^ swz(vd0 + 2)] = c;
            c[0]=(__bf16)r0.w; c[1]=(__bf16)r1.w; c[2]=(__bf16)r2.w; c[3]=(__bf16)r3.w;
            *(bf16x4*)&Vlds[vd0 + 3][vkv ^ swz(vd0 + 3)] = c;
        }
        __syncthreads();

        if (kv0 <= qw + 15) {   // wave-uniform: skip fully-masked tiles
            // --- QK^T: S[16q x 64kv] as 4 C-frags ---
            f32x4 s[4];
            #pragma unroll
            for (int c = 0; c < 4; ++c) {
                f32x4 acc = {};
                #pragma unroll
                for (int eh = 0; eh < 2; ++eh) {
                    bf16x8 kb = *(const bf16x8*)&Klds[c * 16 + li][eh * 32 + g * 8];
                    acc = __builtin_amdgcn_mfma_f32_16x16x32_bf16(qa[eh], kb, acc, 0, 0, 0);
                }
                s[c] = acc;
            }
            // --- additive bias + causal mask (masked lanes skip the load) ---
            #pragma unroll
            for (int j = 0; j < 4; ++j) {
                const int lg = qw + g * 4 + j;
                const float* bp = Bias + (size_t)lg * NS + kv0 + li;
                #pragma unroll
                for (int c = 0; c < 4; ++c) {
                    const int sg = kv0 + c * 16 + li;
                    s[c][j] = (sg <= lg) ? fmaf(bp[c * 16], SC, s[c][j]) : -INFINITY;
                }
            }
            // --- online softmax: row stats across the 16-lane column group ---
            float pm[4];
            #pragma unroll
            for (int j = 0; j < 4; ++j)
                pm[j] = fmaxf(fmaxf(s[0][j], s[1][j]), fmaxf(s[2][j], s[3][j]));
            #pragma unroll
            for (int off = 1; off < 16; off <<= 1) {
                #pragma unroll
                for (int j = 0; j < 4; ++j)
                    pm[j] = fmaxf(pm[j], __shfl_xor(pm[j], off, 64));
            }
            float corr[4];
            #pragma unroll
            for (int j = 0; j < 4; ++j) {
                const float mn = fmaxf(m_run[j], pm[j]);
                corr[j] = exp2f(m_run[j] - mn);
                m_run[j] = mn;
            }
            #pragma unroll
            for (int c = 0; c < 4; ++c) {
                #pragma unroll
                for (int j = 0; j < 4; ++j)
                    s[c][j] = exp2f(s[c][j] - m_run[j]);
            }
            float rs[4];
            #pragma unroll
            for (int j = 0; j < 4; ++j)
                rs[j] = (s[0][j] + s[1][j]) + (s[2][j] + s[3][j]);
            #pragma unroll
            for (int off = 1; off < 16; off <<= 1) {
                #pragma unroll
                for (int j = 0; j < 4; ++j)
                    rs[j] += __shfl_xor(rs[j], off, 64);
            }
            #pragma unroll
            for (int j = 0; j < 4; ++j) {
                l_run[j] = l_run[j] * corr[j] + rs[j];
                o[0][j] *= corr[j]; o[1][j] *= corr[j];
                o[2][j] *= corr[j]; o[3][j] *= corr[j];
            }
            // --- P -> LDS (bf16), re-fragment for PV ---
            #pragma unroll
            for (int c = 0; c < 4; ++c) {
                #pragma unroll
                for (int j = 0; j < 4; ++j)
                    Plds[w][g * 4 + j][c * 16 + li] = (__bf16)s[c][j];
            }
            asm volatile("s_waitcnt lgkmcnt(0)" ::: "memory");
            __builtin_amdgcn_sched_barrier(0);
            bf16x8 pa0 = *(const bf16x8*)&Plds[w][li][g * 8];
            bf16x8 pa1 = *(const bf16x8*)&Plds[w][li][g * 8 + 32];
            // --- PV: O += P @ V ---
            #pragma unroll
            for (int dt = 0; dt < 4; ++dt) {
                const int d = dt * 16 + li;
                bf16x8 v0 = *(const bf16x8*)&Vlds[d][(g * 8) ^ swz(d)];
                bf16x8 v1 = *(const bf16x8*)&Vlds[d][(32 + g * 8) ^ swz(d)];
                o[dt] = __builtin_amdgcn_mfma_f32_16x16x32_bf16(pa0, v0, o[dt], 0, 0, 0);
                o[dt] = __builtin_amdgcn_mfma_f32_16x16x32_bf16(pa1, v1, o[dt], 0, 0, 0);
            }
        }
    }
    // --- epilogue: normalize and store fp32 ---
    #pragma unroll
    for (int j = 0; j < 4; ++j) {
        const float inv = 1.0f / l_run[j];
        const int lg = qw + g * 4 + j;
        float* op = Out + (((size_t)(b * NL + lg)) * NH + h) * ND + li;
        op[0]  = o[0][j] * inv;
        op[16] = o[1][j] * inv;
        op[32] = o[2][j] * inv;
        op[48] = o[3][j] * inv;
    }
}

extern "C" void kernel_launch(void* const* d_in, const int* in_sizes, int n_in,
                              void* d_out, int out_size, void* d_ws, size_t ws_size,
                              hipStream_t stream)
{
    const float* Q    = (const float*)d_in[0];
    const float* K    = (const float*)d_in[1];
    const float* V    = (const float*)d_in[2];
    const float* Bias = (const float*)d_in[3];
    // d_in[4] (attn_mask) is the static triu(k=1) causal mask - handled analytically.
    float* Out = (float*)d_out;
    dim3 grid(NL / 64, NB * NH);
    dim3 block(256);
    fa_fwd<<<grid, block, 0, stream>>>(Q, K, V, Bias, Out);
}

// Round 6
// 134.494 us; speedup vs baseline: 2.3128x; 2.3128x over previous
//
#include <hip/hip_runtime.h>
#include <hip/hip_bf16.h>
#include <math.h>

// CausalFullAttention: out[b,l,h,d] = softmax_s( 0.125*(q.k + bias[l,s]), s<=l ) @ V
// B=4 L=S=2048 H=8 E=D=64, fp32 in/out, bf16 MFMA compute.
// R2 (4th resubmit after infra failures): double-buffered KV + T14 issue-early/write-late
//     staging, bias reg-prefetch, heavy-first XCD-clustered block remap.

typedef __bf16 bf16x8 __attribute__((ext_vector_type(8)));
typedef __bf16 bf16x4 __attribute__((ext_vector_type(4)));
typedef float  f32x4  __attribute__((ext_vector_type(4)));

#define NB 4
#define NL 2048
#define NS 2048
#define NH 8
#define NE 64
#define ND 64

__device__ __forceinline__ int swz(int d) { return ((d ^ (d >> 3)) & 7) << 3; }

__device__ __forceinline__ bf16x8 cvt8s(float4 a, float4 b, float sc) {
    bf16x8 r;
    r[0] = (__bf16)(a.x * sc); r[1] = (__bf16)(a.y * sc);
    r[2] = (__bf16)(a.z * sc); r[3] = (__bf16)(a.w * sc);
    r[4] = (__bf16)(b.x * sc); r[5] = (__bf16)(b.y * sc);
    r[6] = (__bf16)(b.z * sc); r[7] = (__bf16)(b.w * sc);
    return r;
}
__device__ __forceinline__ bf16x8 cvt8(float4 a, float4 b) {
    bf16x8 r;
    r[0] = (__bf16)a.x; r[1] = (__bf16)a.y; r[2] = (__bf16)a.z; r[3] = (__bf16)a.w;
    r[4] = (__bf16)b.x; r[5] = (__bf16)b.y; r[6] = (__bf16)b.z; r[7] = (__bf16)b.w;
    return r;
}

__global__ __launch_bounds__(256)
void fa_fwd(const float* __restrict__ Q, const float* __restrict__ K,
            const float* __restrict__ V, const float* __restrict__ Bias,
            float* __restrict__ Out)
{
    // K tile row-major [kv][e], +8 pad breaks the 128B-row bank conflict. Double-buffered.
    __shared__ __bf16 Klds[2][64][72];
    // V tile transposed [d][kv], XOR-swizzled within rows. Double-buffered.
    __shared__ __bf16 Vlds[2][64][64];
    // per-wave P bounce buffer for the softmax->PV re-fragmentation
    __shared__ __bf16 Plds[4][16][72];

    const int tid  = threadIdx.x;
    const int w    = tid >> 6, lane = tid & 63;
    const int g    = lane >> 4, li = lane & 15;

    // block remap: heavy q-tiles dispatched first; 4 heads clustered per XCD.
    const int id  = blockIdx.x;
    const int xcd = id & 7;
    const int i2  = id >> 3;              // 0..127
    const int bh  = xcd * 4 + (i2 >> 5);  // 0..31
    const int qt  = 31 - (i2 & 31);       // heavy first
    const int b   = bh >> 3, h = bh & 7;
    const int qb  = qt << 6;
    const int qw  = qb + (w << 4);        // this wave's first q row

    // softmax( scale*(qk + bias) ) -> base-2 domain
    const float SC = 0.125f * 1.44269504088896340736f;

    // Q fragments: A[m=li][k = eh*32 + g*8 + j], loaded once, pre-scaled
    bf16x8 qa[2];
    {
        const float* qp = Q + (((size_t)(b * NL + qw + li)) * NH + h) * NE;
        #pragma unroll
        for (int eh = 0; eh < 2; ++eh) {
            const int e0 = eh * 32 + g * 8;
            float4 f0 = *(const float4*)(qp + e0);
            float4 f1 = *(const float4*)(qp + e0 + 4);
            qa[eh] = cvt8s(f0, f1, SC);
        }
    }

    f32x4 o[4] = {};                      // O accum: row = g*4+j, col = dt*16+li
    float m_run[4] = {-INFINITY, -INFINITY, -INFINITY, -INFINITY};
    float l_run[4] = {};

    const int ntiles = qt + 1;            // causal: kv tiles 0 .. qt

    // cooperative staging indices
    const int skv = tid >> 2,        se0 = (tid & 3) << 4;   // K: row, e-quarter
    const int vkv = (tid >> 4) << 2, vd0 = (tid & 15) << 2;  // V: 4kv x 4d sub-block

    const float* kp0 = K + (((size_t)(b * NS + skv)) * NH + h) * NE + se0;
    const float* vp0 = V + (((size_t)(b * NS + vkv)) * NH + h) * ND + vd0;

    float4 ka0, ka1, ka2, ka3;            // K stage regs (tile in flight)
    float4 va0, va1, va2, va3;            // V stage regs
    float bcur[4][4], bnxt[4][4];         // bias regs: [j][c], current / next tile

    // ---- prologue: load + stage tile 0 into buf0, bias tile 0 into regs ----
    {
        ka0 = ((const float4*)kp0)[0]; ka1 = ((const float4*)kp0)[1];
        ka2 = ((const float4*)kp0)[2]; ka3 = ((const float4*)kp0)[3];
        va0 = *(const float4*)(vp0);
        va1 = *(const float4*)(vp0 + NH * ND);
        va2 = *(const float4*)(vp0 + 2 * NH * ND);
        va3 = *(const float4*)(vp0 + 3 * NH * ND);
        #pragma unroll
        for (int j = 0; j < 4; ++j) {
            const float* bp = Bias + (size_t)(qw + g * 4 + j) * NS + li;
            #pragma unroll
            for (int c = 0; c < 4; ++c) bcur[j][c] = bp[c * 16];
        }
        *(bf16x8*)&Klds[0][skv][se0]     = cvt8(ka0, ka1);
        *(bf16x8*)&Klds[0][skv][se0 + 8] = cvt8(ka2, ka3);
        bf16x4 cc;
        cc[0]=(__bf16)va0.x; cc[1]=(__bf16)va1.x; cc[2]=(__bf16)va2.x; cc[3]=(__bf16)va3.x;
        *(bf16x4*)&Vlds[0][vd0 + 0][vkv ^ swz(vd0 + 0)] = cc;
        cc[0]=(__bf16)va0.y; cc[1]=(__bf16)va1.y; cc[2]=(__bf16)va2.y; cc[3]=(__bf16)va3.y;
        *(bf16x4*)&Vlds[0][vd0 + 1][vkv ^ swz(vd0 + 1)] = cc;
        cc[0]=(__bf16)va0.z; cc[1]=(__bf16)va1.z; cc[2]=(__bf16)va2.z; cc[3]=(__bf16)va3.z;
        *(bf16x4*)&Vlds[0][vd0 + 2][vkv ^ swz(vd0 + 2)] = cc;
        cc[0]=(__bf16)va0.w; cc[1]=(__bf16)va1.w; cc[2]=(__bf16)va2.w; cc[3]=(__bf16)va3.w;
        *(bf16x4*)&Vlds[0][vd0 + 3][vkv ^ swz(vd0 + 3)] = cc;
        __syncthreads();
    }

    for (int t = 0; t < ntiles; ++t) {
        const int cur = t & 1;
        const bool more = (t + 1 < ntiles);

        // ---- phase A: issue next tile's global loads (latency hidden under compute) ----
        if (more) {
            const int kvn = (t + 1) << 6;
            const float* kp = kp0 + (size_t)kvn * (NH * NE);
            ka0 = ((const float4*)kp)[0]; ka1 = ((const float4*)kp)[1];
            ka2 = ((const float4*)kp)[2]; ka3 = ((const float4*)kp)[3];
            const float* vp = vp0 + (size_t)kvn * (NH * ND);
            va0 = *(const float4*)(vp);
            va1 = *(const float4*)(vp + NH * ND);
            va2 = *(const float4*)(vp + 2 * NH * ND);
            va3 = *(const float4*)(vp + 3 * NH * ND);
            #pragma unroll
            for (int j = 0; j < 4; ++j) {
                const float* bp = Bias + (size_t)(qw + g * 4 + j) * NS + kvn + li;
                #pragma unroll
                for (int c = 0; c < 4; ++c) bnxt[j][c] = bp[c * 16];
            }
        }

        // ---- phase B: compute tile t from buf[cur] ----
        const int kv0 = t << 6;
        f32x4 s[4];
        #pragma unroll
        for (int c = 0; c < 4; ++c) {
            f32x4 acc = {};
            #pragma unroll
            for (int eh = 0; eh < 2; ++eh) {
                bf16x8 kb = *(const bf16x8*)&Klds[cur][c * 16 + li][eh * 32 + g * 8];
                acc = __builtin_amdgcn_mfma_f32_16x16x32_bf16(qa[eh], kb, acc, 0, 0, 0);
            }
            s[c] = acc;
        }
        // bias (in regs); causal mask only on the diagonal tile
        if (t == ntiles - 1) {
            #pragma unroll
            for (int j = 0; j < 4; ++j) {
                const int lg = qw + g * 4 + j;
                #pragma unroll
                for (int c = 0; c < 4; ++c) {
                    const int sg = kv0 + c * 16 + li;
                    s[c][j] = (sg <= lg) ? fmaf(bcur[j][c], SC, s[c][j]) : -INFINITY;
                }
            }
        } else {
            #pragma unroll
            for (int j = 0; j < 4; ++j)
                #pragma unroll
                for (int c = 0; c < 4; ++c)
                    s[c][j] = fmaf(bcur[j][c], SC, s[c][j]);
        }
        // online softmax: row stats across the 16-lane column group
        float pm[4];
        #pragma unroll
        for (int j = 0; j < 4; ++j)
            pm[j] = fmaxf(fmaxf(s[0][j], s[1][j]), fmaxf(s[2][j], s[3][j]));
        #pragma unroll
        for (int off = 1; off < 16; off <<= 1) {
            #pragma unroll
            for (int j = 0; j < 4; ++j)
                pm[j] = fmaxf(pm[j], __shfl_xor(pm[j], off, 64));
        }
        float corr[4];
        #pragma unroll
        for (int j = 0; j < 4; ++j) {
            const float mn = fmaxf(m_run[j], pm[j]);
            corr[j] = exp2f(m_run[j] - mn);
            m_run[j] = mn;
        }
        #pragma unroll
        for (int c = 0; c < 4; ++c) {
            #pragma unroll
            for (int j = 0; j < 4; ++j)
                s[c][j] = exp2f(s[c][j] - m_run[j]);
        }
        float rs[4];
        #pragma unroll
        for (int j = 0; j < 4; ++j)
            rs[j] = (s[0][j] + s[1][j]) + (s[2][j] + s[3][j]);
        #pragma unroll
        for (int off = 1; off < 16; off <<= 1) {
            #pragma unroll
            for (int j = 0; j < 4; ++j)
                rs[j] += __shfl_xor(rs[j], off, 64);
        }
        #pragma unroll
        for (int j = 0; j < 4; ++j) {
            l_run[j] = l_run[j] * corr[j] + rs[j];
            o[0][j] *= corr[j]; o[1][j] *= corr[j];
            o[2][j] *= corr[j]; o[3][j] *= corr[j];
        }
        // P -> LDS (bf16), re-fragment for PV
        #pragma unroll
        for (int c = 0; c < 4; ++c) {
            #pragma unroll
            for (int j = 0; j < 4; ++j)
                Plds[w][g * 4 + j][c * 16 + li] = (__bf16)s[c][j];
        }
        asm volatile("s_waitcnt lgkmcnt(0)" ::: "memory");
        __builtin_amdgcn_sched_barrier(0);
        bf16x8 pa0 = *(const bf16x8*)&Plds[w][li][g * 8];
        bf16x8 pa1 = *(const bf16x8*)&Plds[w][li][g * 8 + 32];
        // PV: O += P @ V
        #pragma unroll
        for (int dt = 0; dt < 4; ++dt) {
            const int d = dt * 16 + li;
            bf16x8 v0 = *(const bf16x8*)&Vlds[cur][d][(g * 8) ^ swz(d)];
            bf16x8 v1 = *(const bf16x8*)&Vlds[cur][d][(32 + g * 8) ^ swz(d)];
            o[dt] = __builtin_amdgcn_mfma_f32_16x16x32_bf16(pa0, v0, o[dt], 0, 0, 0);
            o[dt] = __builtin_amdgcn_mfma_f32_16x16x32_bf16(pa1, v1, o[dt], 0, 0, 0);
        }

        // ---- phase C/D: write next tile into the other buffer ----
        if (more) {
            __syncthreads();   // all waves done reading buf[cur^1] (iter t-1)
            const int nxt = cur ^ 1;
            *(bf16x8*)&Klds[nxt][skv][se0]     = cvt8(ka0, ka1);
            *(bf16x8*)&Klds[nxt][skv][se0 + 8] = cvt8(ka2, ka3);
            bf16x4 cc;
            cc[0]=(__bf16)va0.x; cc[1]=(__bf16)va1.x; cc[2]=(__bf16)va2.x; cc[3]=(__bf16)va3.x;
            *(bf16x4*)&Vlds[nxt][vd0 + 0][vkv ^ swz(vd0 + 0)] = cc;
            cc[0]=(__bf16)va0.y; cc[1]=(__bf16)va1.y; cc[2]=(__bf16)va2.y; cc[3]=(__bf16)va3.y;
            *(bf16x4*)&Vlds[nxt][vd0 + 1][vkv ^ swz(vd0 + 1)] = cc;
            cc[0]=(__bf16)va0.z; cc[1]=(__bf16)va1.z; cc[2]=(__bf16)va2.z; cc[3]=(__bf16)va3.z;
            *(bf16x4*)&Vlds[nxt][vd0 + 2][vkv ^ swz(vd0 + 2)] = cc;
            cc[0]=(__bf16)va0.w; cc[1]=(__bf16)va1.w; cc[2]=(__bf16)va2.w; cc[3]=(__bf16)va3.w;
            *(bf16x4*)&Vlds[nxt][vd0 + 3][vkv ^ swz(vd0 + 3)] = cc;
            __syncthreads();   // writes visible before compute t+1
            #pragma unroll
            for (int j = 0; j < 4; ++j)
                #pragma unroll
                for (int c = 0; c < 4; ++c) bcur[j][c] = bnxt[j][c];
        }
    }

    // ---- epilogue: normalize and store fp32 ----
    #pragma unroll
    for (int j = 0; j < 4; ++j) {
        const float inv = 1.0f / l_run[j];
        const int lg = qw + g * 4 + j;
        float* op = Out + (((size_t)(b * NL + lg)) * NH + h) * ND + li;
        op[0]  = o[0][j] * inv;
        op[16] = o[1][j] * inv;
        op[32] = o[2][j] * inv;
        op[48] = o[3][j] * inv;
    }
}

extern "C" void kernel_launch(void* const* d_in, const int* in_sizes, int n_in,
                              void* d_out, int out_size, void* d_ws, size_t ws_size,
                              hipStream_t stream)
{
    const float* Q    = (const float*)d_in[0];
    const float* K    = (const float*)d_in[1];
    const float* V    = (const float*)d_in[2];
    const float* Bias = (const float*)d_in[3];
    // d_in[4] (attn_mask) is the static triu(k=1) causal mask - handled analytically.
    float* Out = (float*)d_out;
    dim3 grid(NL / 64 * NB * NH);   // 1024 blocks, remapped in-kernel
    dim3 block(256);
    fa_fwd<<<grid, block, 0, stream>>>(Q, K, V, Bias, Out);
}

// Round 8
// 128.716 us; speedup vs baseline: 2.4166x; 1.0449x over previous
//
#include <hip/hip_runtime.h>
#include <hip/hip_bf16.h>
#include <math.h>

// CausalFullAttention: out[b,l,h,d] = softmax_s( 0.125*(q.k + bias[l,s]), s<=l ) @ V
// B=4 L=S=2048 H=8 E=D=64, fp32 in/out, bf16 MFMA compute.
// R7: R6 with the causal-straddle condition fixed (kv0+63 > qw, not qw+15).
//     8-wave 512-thread blocks, QBLK=128 (KV tile 64) -> 512 blocks, ALL resident
//     (2 blocks/CU at 52KB LDS); complementary heavy/light dispatch pairing.

typedef __bf16 bf16x8 __attribute__((ext_vector_type(8)));
typedef __bf16 bf16x2 __attribute__((ext_vector_type(2)));
typedef float  f32x4  __attribute__((ext_vector_type(4)));

#define NB 4
#define NL 2048
#define NS 2048
#define NH 8
#define NE 64
#define ND 64

__device__ __forceinline__ int swz(int d) { return ((d ^ (d >> 3)) & 7) << 3; }

__device__ __forceinline__ bf16x8 cvt8s(float4 a, float4 b, float sc) {
    bf16x8 r;
    r[0] = (__bf16)(a.x * sc); r[1] = (__bf16)(a.y * sc);
    r[2] = (__bf16)(a.z * sc); r[3] = (__bf16)(a.w * sc);
    r[4] = (__bf16)(b.x * sc); r[5] = (__bf16)(b.y * sc);
    r[6] = (__bf16)(b.z * sc); r[7] = (__bf16)(b.w * sc);
    return r;
}
__device__ __forceinline__ bf16x8 cvt8(float4 a, float4 b) {
    bf16x8 r;
    r[0] = (__bf16)a.x; r[1] = (__bf16)a.y; r[2] = (__bf16)a.z; r[3] = (__bf16)a.w;
    r[4] = (__bf16)b.x; r[5] = (__bf16)b.y; r[6] = (__bf16)b.z; r[7] = (__bf16)b.w;
    return r;
}

__global__ __launch_bounds__(512)
void fa_fwd(const float* __restrict__ Q, const float* __restrict__ K,
            const float* __restrict__ V, const float* __restrict__ Bias,
            float* __restrict__ Out)
{
    // K tile row-major [kv][e], +8 pad breaks the 128B-row bank conflict. Double-buffered.
    __shared__ __bf16 Klds[2][64][72];
    // V tile transposed [d][kv], XOR-swizzled within rows. Double-buffered.
    __shared__ __bf16 Vlds[2][64][64];
    // per-wave P bounce buffer for the softmax->PV re-fragmentation
    __shared__ __bf16 Plds[8][16][72];

    const int tid  = threadIdx.x;
    const int w    = tid >> 6, lane = tid & 63;
    const int g    = lane >> 4, li = lane & 15;

    // 512 blocks, all resident (2/CU). Complementary pairing: blocks i and i+256
    // (which land on the same CU under linear fill) carry q-sizes summing to ~const.
    const int id = blockIdx.x;
    int bh, qp_;
    if (id < 256) { bh = id >> 4;                qp_ = 15 - (id & 15); }
    else          { bh = 16 + ((id - 256) >> 4); qp_ = id & 15;        }
    const int b   = bh >> 3, h = bh & 7;
    const int qb  = qp_ << 7;             // 128-row q block
    const int qw  = qb + (w << 4);        // this wave's first q row

    // softmax( scale*(qk + bias) ) -> base-2 domain
    const float SC = 0.125f * 1.44269504088896340736f;

    // Q fragments: A[m=li][k = eh*32 + g*8 + j], loaded once, pre-scaled
    bf16x8 qa[2];
    {
        const float* qp = Q + (((size_t)(b * NL + qw + li)) * NH + h) * NE;
        #pragma unroll
        for (int eh = 0; eh < 2; ++eh) {
            const int e0 = eh * 32 + g * 8;
            float4 f0 = *(const float4*)(qp + e0);
            float4 f1 = *(const float4*)(qp + e0 + 4);
            qa[eh] = cvt8s(f0, f1, SC);
        }
    }

    f32x4 o[4] = {};                      // O accum: row = g*4+j, col = dt*16+li
    float m_run[4] = {-INFINITY, -INFINITY, -INFINITY, -INFINITY};
    float l_run[4] = {};

    const int ntiles = (qb >> 6) + 2;     // kv tiles cover rows 0 .. qb+127

    // cooperative staging indices (512 threads)
    const int skv = tid >> 3,        se0 = (tid & 7) << 3;   // K: row, 8-float chunk
    const int vkv = (tid >> 4) << 1, vd0 = (tid & 15) << 2;  // V: 2kv x 4d sub-block

    const float* kp0 = K + (((size_t)(b * NS + skv)) * NH + h) * NE + se0;
    const float* vp0 = V + (((size_t)(b * NS + vkv)) * NH + h) * ND + vd0;

    float4 ka0, ka1;                      // K stage regs (tile in flight)
    float4 va0, va1;                      // V stage regs (2 kv rows)
    float bcur[4][4], bnxt[4][4];         // bias regs: [j][c], current / next tile

    // ---- prologue: load + stage tile 0 into buf0, bias tile 0 into regs ----
    {
        ka0 = ((const float4*)kp0)[0]; ka1 = ((const float4*)kp0)[1];
        va0 = *(const float4*)(vp0);
        va1 = *(const float4*)(vp0 + NH * ND);
        #pragma unroll
        for (int j = 0; j < 4; ++j) {
            const float* bp = Bias + (size_t)(qw + g * 4 + j) * NS + li;
            #pragma unroll
            for (int c = 0; c < 4; ++c) bcur[j][c] = bp[c * 16];
        }
        *(bf16x8*)&Klds[0][skv][se0] = cvt8(ka0, ka1);
        const float* f0 = (const float*)&va0;
        const float* f1 = (const float*)&va1;
        #pragma unroll
        for (int dd = 0; dd < 4; ++dd) {
            bf16x2 cc;
            cc[0] = (__bf16)f0[dd]; cc[1] = (__bf16)f1[dd];
            *(bf16x2*)&Vlds[0][vd0 + dd][vkv ^ swz(vd0 + dd)] = cc;
        }
        __syncthreads();
    }

    for (int t = 0; t < ntiles; ++t) {
        const int cur = t & 1;
        const bool more = (t + 1 < ntiles);

        // ---- phase A: issue next tile's global loads (latency hidden under compute) ----
        if (more) {
            const int kvn = (t + 1) << 6;
            const float* kp = kp0 + (size_t)kvn * (NH * NE);
            ka0 = ((const float4*)kp)[0]; ka1 = ((const float4*)kp)[1];
            const float* vp = vp0 + (size_t)kvn * (NH * ND);
            va0 = *(const float4*)(vp);
            va1 = *(const float4*)(vp + NH * ND);
            #pragma unroll
            for (int j = 0; j < 4; ++j) {
                const float* bp = Bias + (size_t)(qw + g * 4 + j) * NS + kvn + li;
                #pragma unroll
                for (int c = 0; c < 4; ++c) bnxt[j][c] = bp[c * 16];
            }
        }

        // ---- phase B: compute tile t from buf[cur] (wave-uniform causal skip) ----
        const int kv0 = t << 6;
        if (kv0 <= qw + 15) {
            f32x4 s[4];
            #pragma unroll
            for (int c = 0; c < 4; ++c) {
                f32x4 acc = {};
                #pragma unroll
                for (int eh = 0; eh < 2; ++eh) {
                    bf16x8 kb = *(const bf16x8*)&Klds[cur][c * 16 + li][eh * 32 + g * 8];
                    acc = __builtin_amdgcn_mfma_f32_16x16x32_bf16(qa[eh], kb, acc, 0, 0, 0);
                }
                s[c] = acc;
            }
            // bias (in regs); causal select on any tile whose top kv exceeds the
            // wave's FIRST row (kv0+63 > qw) -- R6 bug was comparing vs qw+15.
            if (kv0 + 63 > qw) {
                #pragma unroll
                for (int j = 0; j < 4; ++j) {
                    const int lg = qw + g * 4 + j;
                    #pragma unroll
                    for (int c = 0; c < 4; ++c) {
                        const int sg = kv0 + c * 16 + li;
                        s[c][j] = (sg <= lg) ? fmaf(bcur[j][c], SC, s[c][j]) : -INFINITY;
                    }
                }
            } else {
                #pragma unroll
                for (int j = 0; j < 4; ++j)
                    #pragma unroll
                    for (int c = 0; c < 4; ++c)
                        s[c][j] = fmaf(bcur[j][c], SC, s[c][j]);
            }
            // online softmax: row stats across the 16-lane column group
            float pm[4];
            #pragma unroll
            for (int j = 0; j < 4; ++j)
                pm[j] = fmaxf(fmaxf(s[0][j], s[1][j]), fmaxf(s[2][j], s[3][j]));
            #pragma unroll
            for (int off = 1; off < 16; off <<= 1) {
                #pragma unroll
                for (int j = 0; j < 4; ++j)
                    pm[j] = fmaxf(pm[j], __shfl_xor(pm[j], off, 64));
            }
            float corr[4];
            #pragma unroll
            for (int j = 0; j < 4; ++j) {
                const float mn = fmaxf(m_run[j], pm[j]);
                corr[j] = exp2f(m_run[j] - mn);
                m_run[j] = mn;
            }
            #pragma unroll
            for (int c = 0; c < 4; ++c) {
                #pragma unroll
                for (int j = 0; j < 4; ++j)
                    s[c][j] = exp2f(s[c][j] - m_run[j]);
            }
            float rs[4];
            #pragma unroll
            for (int j = 0; j < 4; ++j)
                rs[j] = (s[0][j] + s[1][j]) + (s[2][j] + s[3][j]);
            #pragma unroll
            for (int off = 1; off < 16; off <<= 1) {
                #pragma unroll
                for (int j = 0; j < 4; ++j)
                    rs[j] += __shfl_xor(rs[j], off, 64);
            }
            #pragma unroll
            for (int j = 0; j < 4; ++j) {
                l_run[j] = l_run[j] * corr[j] + rs[j];
                o[0][j] *= corr[j]; o[1][j] *= corr[j];
                o[2][j] *= corr[j]; o[3][j] *= corr[j];
            }
            // P -> LDS (bf16), re-fragment for PV
            #pragma unroll
            for (int c = 0; c < 4; ++c) {
                #pragma unroll
                for (int j = 0; j < 4; ++j)
                    Plds[w][g * 4 + j][c * 16 + li] = (__bf16)s[c][j];
            }
            asm volatile("s_waitcnt lgkmcnt(0)" ::: "memory");
            __builtin_amdgcn_sched_barrier(0);
            bf16x8 pa0 = *(const bf16x8*)&Plds[w][li][g * 8];
            bf16x8 pa1 = *(const bf16x8*)&Plds[w][li][g * 8 + 32];
            // PV: O += P @ V
            #pragma unroll
            for (int dt = 0; dt < 4; ++dt) {
                const int d = dt * 16 + li;
                bf16x8 v0 = *(const bf16x8*)&Vlds[cur][d][(g * 8) ^ swz(d)];
                bf16x8 v1 = *(const bf16x8*)&Vlds[cur][d][(32 + g * 8) ^ swz(d)];
                o[dt] = __builtin_amdgcn_mfma_f32_16x16x32_bf16(pa0, v0, o[dt], 0, 0, 0);
                o[dt] = __builtin_amdgcn_mfma_f32_16x16x32_bf16(pa1, v1, o[dt], 0, 0, 0);
            }
        }

        // ---- phase C/D: write next tile into the other buffer (all threads) ----
        if (more) {
            __syncthreads();   // all waves done reading buf[cur^1] (iter t-1)
            const int nxt = cur ^ 1;
            *(bf16x8*)&Klds[nxt][skv][se0] = cvt8(ka0, ka1);
            const float* f0 = (const float*)&va0;
            const float* f1 = (const float*)&va1;
            #pragma unroll
            for (int dd = 0; dd < 4; ++dd) {
                bf16x2 cc;
                cc[0] = (__bf16)f0[dd]; cc[1] = (__bf16)f1[dd];
                *(bf16x2*)&Vlds[nxt][vd0 + dd][vkv ^ swz(vd0 + dd)] = cc;
            }
            __syncthreads();   // writes visible before compute t+1
            #pragma unroll
            for (int j = 0; j < 4; ++j)
                #pragma unroll
                for (int c = 0; c < 4; ++c) bcur[j][c] = bnxt[j][c];
        }
    }

    // ---- epilogue: normalize and store fp32 ----
    #pragma unroll
    for (int j = 0; j < 4; ++j) {
        const float inv = 1.0f / l_run[j];
        const int lg = qw + g * 4 + j;
        float* op = Out + (((size_t)(b * NL + lg)) * NH + h) * ND + li;
        op[0]  = o[0][j] * inv;
        op[16] = o[1][j] * inv;
        op[32] = o[2][j] * inv;
        op[48] = o[3][j] * inv;
    }
}

extern "C" void kernel_launch(void* const* d_in, const int* in_sizes, int n_in,
                              void* d_out, int out_size, void* d_ws, size_t ws_size,
                              hipStream_t stream)
{
    const float* Q    = (const float*)d_in[0];
    const float* K    = (const float*)d_in[1];
    const float* V    = (const float*)d_in[2];
    const float* Bias = (const float*)d_in[3];
    // d_in[4] (attn_mask) is the static triu(k=1) causal mask - handled analytically.
    float* Out = (float*)d_out;
    dim3 grid(NL / 128 * NB * NH);   // 512 blocks, remapped in-kernel
    dim3 block(512);
    fa_fwd<<<grid, block, 0, stream>>>(Q, K, V, Bias, Out);
}